// Round 1
// baseline (768.696 us; speedup 1.0000x reference)
//
#include <hip/hip_runtime.h>
#include <hip/hip_bf16.h>

#define DDIM 128

typedef float  f32x16 __attribute__((ext_vector_type(16)));
typedef float  f32x4  __attribute__((ext_vector_type(4)));
typedef short  bf16x8 __attribute__((ext_vector_type(8)));

__device__ __forceinline__ short f2bf(float f) {
    union { float f; unsigned u; } v; v.f = f;
    unsigned u = v.u;
    unsigned r = (u + 0x7fffu + ((u >> 16) & 1u)) >> 16;   // RNE
    return (short)r;
}

__device__ __forceinline__ bf16x8 cvt8(f32x4 a, f32x4 b) {
    bf16x8 r;
    r[0]=f2bf(a[0]); r[1]=f2bf(a[1]); r[2]=f2bf(a[2]); r[3]=f2bf(a[3]);
    r[4]=f2bf(b[0]); r[5]=f2bf(b[1]); r[6]=f2bf(b[2]); r[7]=f2bf(b[3]);
    return r;
}

// ---- kernel 0: convert weights to bf16, build W1cat = [W_e | W_s | W_d] [128][384], W2 [128][128]
__global__ void prep_weights(const float* __restrict__ we, const float* __restrict__ wsrc,
                             const float* __restrict__ wdst, const float* __restrict__ wout,
                             short* __restrict__ w1cat, short* __restrict__ w2) {
    int tid = blockIdx.x * 256 + threadIdx.x;        // 65536 total
    if (tid < 128 * 384) {
        int n = tid / 384, k = tid % 384;
        const float* src = (k < 128) ? we : ((k < 256) ? wsrc : wdst);
        w1cat[tid] = f2bf(src[n * 128 + (k & 127)]);
    } else {
        int t2 = tid - 128 * 384;                    // 16384 elems
        w2[t2] = f2bf(wout[t2]);
    }
}

// ---- fused edge kernel: [efeat|src|dst] @ W1catT + b0 -> SiLU -> @W2T + b_out -> LayerNorm
__global__ __launch_bounds__(256) void edge_kernel(
    const float* __restrict__ efeat, const float* __restrict__ src_feat,
    const float* __restrict__ dst_feat, const int* __restrict__ src_idx,
    const int* __restrict__ dst_idx, const float* __restrict__ b0,
    const float* __restrict__ b_out, const float* __restrict__ ln_g,
    const float* __restrict__ ln_b, const short* __restrict__ w1cat,
    const short* __restrict__ w2, float* __restrict__ out, int E)
{
    __shared__ unsigned char smem[4 * 8192];          // per-wave h staging (32 rows x 128 bf16)

    const int tid  = threadIdx.x;
    const int wave = tid >> 6;
    const int lane = tid & 63;
    const int lo   = lane & 31;
    const int hi   = lane >> 5;
    const int ebase = blockIdx.x * 128 + wave * 32;

    // A-operand row for this lane (both hi halves cover the same edge row)
    const int erow = ebase + lo;
    const int ecl  = erow < E ? erow : E - 1;
    const int sidx = src_idx[ecl];
    const int didx = dst_idx[ecl];
    const float* pe = efeat    + (size_t)ecl  * DDIM;
    const float* ps = src_feat + (size_t)sidx * DDIM;
    const float* pd = dst_feat + (size_t)didx * DDIM;

    // per-lane column params, col n = 32*t + lo
    float b0v[4], bov[4], gv[4], bv[4];
#pragma unroll
    for (int t = 0; t < 4; ++t) {
        int n = 32 * t + lo;
        b0v[t] = b0[n]; bov[t] = b_out[n]; gv[t] = ln_g[n]; bv[t] = ln_b[n];
    }

    const int coff = 8 * hi;   // k sub-offset within a 16-wide K step

    // ---------------- GEMM1: K = 384 (efeat | src | dst), acc starts at b0 ----------------
    f32x16 acc[4];
#pragma unroll
    for (int t = 0; t < 4; ++t)
#pragma unroll
        for (int r = 0; r < 16; ++r) acc[t][r] = b0v[t];

#pragma unroll
    for (int seg = 0; seg < 3; ++seg) {
        const float* p = (seg == 0) ? pe : ((seg == 1) ? ps : pd);
#pragma unroll
        for (int ks = 0; ks < 8; ++ks) {
            const f32x4* pv = (const f32x4*)(p + 16 * ks + coff);
            f32x4 fa, fb;
            if (seg == 0) { fa = __builtin_nontemporal_load(pv); fb = __builtin_nontemporal_load(pv + 1); }
            else          { fa = pv[0];                          fb = pv[1]; }
            bf16x8 a = cvt8(fa, fb);
            const int s = seg * 8 + ks;
#pragma unroll
            for (int t = 0; t < 4; ++t) {
                bf16x8 b = *(const bf16x8*)(w1cat + ((32 * t + lo) * 384 + 16 * s + coff));
                acc[t] = __builtin_amdgcn_mfma_f32_32x32x16_bf16(a, b, acc[t], 0, 0, 0);
            }
        }
    }

    // ---------------- SiLU + stage h to LDS (bf16, XOR-swizzled rows) ----------------
    unsigned char* hb = smem + wave * 8192;
#pragma unroll
    for (int r = 0; r < 16; ++r) {
        const int m  = (r & 3) + 8 * (r >> 2) + 4 * hi;   // D-layout row
        const int sw = (m & 7) << 4;
#pragma unroll
        for (int t = 0; t < 4; ++t) {
            float x = acc[t][r];
            float s = x / (1.0f + __expf(-x));            // SiLU
            *(short*)(hb + m * 256 + ((64 * t + 2 * lo) ^ sw)) = f2bf(s);
        }
    }
    __syncthreads();

    // ---------------- GEMM2: y = silu(h) @ W2^T + b_out ----------------
    f32x16 acc2[4];
#pragma unroll
    for (int t = 0; t < 4; ++t)
#pragma unroll
        for (int r = 0; r < 16; ++r) acc2[t][r] = bov[t];

    const int rsw = (lo & 7) << 4;
#pragma unroll
    for (int s = 0; s < 8; ++s) {
        bf16x8 a = *(const bf16x8*)(hb + lo * 256 + ((32 * s + 16 * hi) ^ rsw));
#pragma unroll
        for (int t = 0; t < 4; ++t) {
            bf16x8 b = *(const bf16x8*)(w2 + ((32 * t + lo) * 128 + 16 * s + coff));
            acc2[t] = __builtin_amdgcn_mfma_f32_32x32x16_bf16(a, b, acc2[t], 0, 0, 0);
        }
    }

    // ---------------- LayerNorm over D=128 per edge row + store ----------------
#pragma unroll
    for (int r = 0; r < 16; ++r) {
        float s1 = acc2[0][r] + acc2[1][r] + acc2[2][r] + acc2[3][r];
        float s2 = acc2[0][r]*acc2[0][r] + acc2[1][r]*acc2[1][r]
                 + acc2[2][r]*acc2[2][r] + acc2[3][r]*acc2[3][r];
#pragma unroll
        for (int msk = 1; msk < 32; msk <<= 1) {
            s1 += __shfl_xor(s1, msk, 64);
            s2 += __shfl_xor(s2, msk, 64);
        }
        const float mu   = s1 * (1.0f / 128.0f);
        const float var  = s2 * (1.0f / 128.0f) - mu * mu;
        const float rstd = rsqrtf(var + 1e-5f);
        const int   m    = (r & 3) + 8 * (r >> 2) + 4 * hi;
        const int   eo   = ebase + m;
        if (eo < E) {
            float* po = out + (size_t)eo * DDIM;
#pragma unroll
            for (int t = 0; t < 4; ++t) {
                float o = (acc2[t][r] - mu) * rstd * gv[t] + bv[t];
                __builtin_nontemporal_store(o, po + 32 * t + lo);
            }
        }
    }
}

extern "C" void kernel_launch(void* const* d_in, const int* in_sizes, int n_in,
                              void* d_out, int out_size, void* d_ws, size_t ws_size,
                              hipStream_t stream)
{
    const float* efeat    = (const float*)d_in[0];
    const float* src_feat = (const float*)d_in[1];
    const float* dst_feat = (const float*)d_in[2];
    const int*   src_idx  = (const int*)d_in[3];
    const int*   dst_idx  = (const int*)d_in[4];
    const float* w_efeat  = (const float*)d_in[5];
    const float* w_src    = (const float*)d_in[6];
    const float* w_dst    = (const float*)d_in[7];
    const float* b0       = (const float*)d_in[8];
    const float* w_out    = (const float*)d_in[9];
    const float* b_out    = (const float*)d_in[10];
    const float* ln_g     = (const float*)d_in[11];
    const float* ln_b     = (const float*)d_in[12];
    float* out = (float*)d_out;
    const int E = in_sizes[3];

    short* w1cat = (short*)d_ws;                          // 128*384 bf16 = 96 KB
    short* w2    = (short*)((char*)d_ws + 128 * 384 * 2); // 128*128 bf16 = 32 KB

    prep_weights<<<256, 256, 0, stream>>>(w_efeat, w_src, w_dst, w_out, w1cat, w2);

    const int nb = (E + 127) / 128;
    edge_kernel<<<nb, 256, 0, stream>>>(efeat, src_feat, dst_feat, src_idx, dst_idx,
                                        b0, b_out, ln_g, ln_b, w1cat, w2, out, E);
}

// Round 2
// 513.529 us; speedup vs baseline: 1.4969x; 1.4969x over previous
//
#include <hip/hip_runtime.h>
#include <hip/hip_bf16.h>

#define DDIM 128

typedef float  f32x16 __attribute__((ext_vector_type(16)));
typedef float  f32x4  __attribute__((ext_vector_type(4)));
typedef short  bf16x8 __attribute__((ext_vector_type(8)));

__device__ __forceinline__ short f2bf(float f) {
    union { float f; unsigned u; } v; v.f = f;
    unsigned u = v.u;
    unsigned r = (u + 0x7fffu + ((u >> 16) & 1u)) >> 16;   // RNE
    return (short)r;
}

__device__ __forceinline__ bf16x8 cvt8(f32x4 a, f32x4 b) {
    bf16x8 r;
    r[0]=f2bf(a[0]); r[1]=f2bf(a[1]); r[2]=f2bf(a[2]); r[3]=f2bf(a[3]);
    r[4]=f2bf(b[0]); r[5]=f2bf(b[1]); r[6]=f2bf(b[2]); r[7]=f2bf(b[3]);
    return r;
}

// ---- kernel 0: build FRAGMENT-MAJOR bf16 weights.
// W1frag layout: [s(24)][n(128)][hi(2)][k8(8)] where logical col = 16*s + 8*hi + k8
//   of W1cat = [W_e | W_s | W_d] (row n = output col, 384 K-cols).
// W2frag layout: [s(8)][n(128)][hi(2)][k8(8)], col = 16*s + 8*hi + k8 of w_out.
// A wave's B-fragment load (lanes lo=0..31,hi=0..1) is then 1KB contiguous.
__global__ void prep_weights(const float* __restrict__ we, const float* __restrict__ wsrc,
                             const float* __restrict__ wdst, const float* __restrict__ wout,
                             short* __restrict__ w1frag, short* __restrict__ w2frag) {
    int tid = blockIdx.x * 256 + threadIdx.x;        // 65536 total
    if (tid < 24 * 128 * 16) {                       // 49152 = 96KB W1
        int k8 = tid & 7;
        int hi = (tid >> 3) & 1;
        int n  = (tid >> 4) & 127;
        int s  = tid >> 11;
        int col = 16 * s + 8 * hi + k8;              // 0..383
        const float* src = (col < 128) ? we : ((col < 256) ? wsrc : wdst);
        w1frag[tid] = f2bf(src[n * 128 + (col & 127)]);
    } else {
        int t2 = tid - 24 * 128 * 16;                // 16384 = 32KB W2
        int k8 = t2 & 7;
        int hi = (t2 >> 3) & 1;
        int n  = (t2 >> 4) & 127;
        int s  = t2 >> 11;
        int col = 16 * s + 8 * hi + k8;              // 0..127
        w2frag[t2] = f2bf(wout[n * 128 + col]);
    }
}

// ---- fused edge kernel: [efeat|src|dst] @ W1catT + b0 -> SiLU -> @W2T + b_out -> LayerNorm
__global__ __launch_bounds__(256) void edge_kernel(
    const float* __restrict__ efeat, const float* __restrict__ src_feat,
    const float* __restrict__ dst_feat, const int* __restrict__ src_idx,
    const int* __restrict__ dst_idx, const float* __restrict__ b0,
    const float* __restrict__ b_out, const float* __restrict__ ln_g,
    const float* __restrict__ ln_b, const short* __restrict__ w1frag,
    const short* __restrict__ w2frag, float* __restrict__ out, int E)
{
    __shared__ unsigned char smem[4 * 8192];          // per-wave h staging (32 rows x 128 bf16)

    const int tid  = threadIdx.x;
    const int wave = tid >> 6;
    const int lane = tid & 63;
    const int lo   = lane & 31;
    const int hi   = lane >> 5;
    const int ebase = blockIdx.x * 128 + wave * 32;

    // A-operand row for this lane (both hi halves cover the same edge row)
    const int erow = ebase + lo;
    const int ecl  = erow < E ? erow : E - 1;
    const int sidx = src_idx[ecl];
    const int didx = dst_idx[ecl];
    const float* pe = efeat    + (size_t)ecl  * DDIM;
    const float* ps = src_feat + (size_t)sidx * DDIM;
    const float* pd = dst_feat + (size_t)didx * DDIM;

    // per-lane column params, col n = 32*t + lo
    float b0v[4], bov[4], gv[4], bv[4];
#pragma unroll
    for (int t = 0; t < 4; ++t) {
        int n = 32 * t + lo;
        b0v[t] = b0[n]; bov[t] = b_out[n]; gv[t] = ln_g[n]; bv[t] = ln_b[n];
    }

    const int coff = 8 * hi;   // k sub-offset within a 16-wide K step
    // per-lane fragment slot within a [n][hi] step-block: ((n)*2+hi)*8 shorts
    const int fslot = ((lo * 2) + hi) * 8;            // + 32*t*16 per tile

    // ---------------- GEMM1: K = 384 (efeat | src | dst), acc starts at b0 ----------------
    f32x16 acc[4];
#pragma unroll
    for (int t = 0; t < 4; ++t)
#pragma unroll
        for (int r = 0; r < 16; ++r) acc[t][r] = b0v[t];

#pragma unroll
    for (int seg = 0; seg < 3; ++seg) {
        const float* p = (seg == 0) ? pe : ((seg == 1) ? ps : pd);
#pragma unroll
        for (int ks = 0; ks < 8; ++ks) {
            const f32x4* pv = (const f32x4*)(p + 16 * ks + coff);
            f32x4 fa, fb;
            if (seg == 0) { fa = __builtin_nontemporal_load(pv); fb = __builtin_nontemporal_load(pv + 1); }
            else          { fa = pv[0];                          fb = pv[1]; }
            bf16x8 a = cvt8(fa, fb);
            const int s = seg * 8 + ks;
            const short* wbase = w1frag + s * (128 * 16) + fslot;
#pragma unroll
            for (int t = 0; t < 4; ++t) {
                bf16x8 b = *(const bf16x8*)(wbase + 32 * t * 16);
                acc[t] = __builtin_amdgcn_mfma_f32_32x32x16_bf16(a, b, acc[t], 0, 0, 0);
            }
        }
    }

    // ---------------- SiLU + stage h to LDS (bf16, XOR-swizzled rows) ----------------
    unsigned char* hb = smem + wave * 8192;
#pragma unroll
    for (int r = 0; r < 16; ++r) {
        const int m  = (r & 3) + 8 * (r >> 2) + 4 * hi;   // D-layout row
        const int sw = (m & 7) << 4;
#pragma unroll
        for (int t = 0; t < 4; ++t) {
            float x = acc[t][r];
            float s = x / (1.0f + __expf(-x));            // SiLU
            *(short*)(hb + m * 256 + ((64 * t + 2 * lo) ^ sw)) = f2bf(s);
        }
    }
    __syncthreads();

    // ---------------- GEMM2: y = silu(h) @ W2^T + b_out ----------------
    f32x16 acc2[4];
#pragma unroll
    for (int t = 0; t < 4; ++t)
#pragma unroll
        for (int r = 0; r < 16; ++r) acc2[t][r] = bov[t];

    const int rsw = (lo & 7) << 4;
#pragma unroll
    for (int s = 0; s < 8; ++s) {
        bf16x8 a = *(const bf16x8*)(hb + lo * 256 + ((32 * s + 16 * hi) ^ rsw));
        const short* wbase = w2frag + s * (128 * 16) + fslot;
#pragma unroll
        for (int t = 0; t < 4; ++t) {
            bf16x8 b = *(const bf16x8*)(wbase + 32 * t * 16);
            acc2[t] = __builtin_amdgcn_mfma_f32_32x32x16_bf16(a, b, acc2[t], 0, 0, 0);
        }
    }

    // ---------------- LayerNorm over D=128 per edge row + store ----------------
#pragma unroll
    for (int r = 0; r < 16; ++r) {
        float s1 = acc2[0][r] + acc2[1][r] + acc2[2][r] + acc2[3][r];
        float s2 = acc2[0][r]*acc2[0][r] + acc2[1][r]*acc2[1][r]
                 + acc2[2][r]*acc2[2][r] + acc2[3][r]*acc2[3][r];
#pragma unroll
        for (int msk = 1; msk < 32; msk <<= 1) {
            s1 += __shfl_xor(s1, msk, 64);
            s2 += __shfl_xor(s2, msk, 64);
        }
        const float mu   = s1 * (1.0f / 128.0f);
        const float var  = s2 * (1.0f / 128.0f) - mu * mu;
        const float rstd = rsqrtf(var + 1e-5f);
        const int   m    = (r & 3) + 8 * (r >> 2) + 4 * hi;
        const int   eo   = ebase + m;
        if (eo < E) {
            float* po = out + (size_t)eo * DDIM;
#pragma unroll
            for (int t = 0; t < 4; ++t) {
                float o = (acc2[t][r] - mu) * rstd * gv[t] + bv[t];
                __builtin_nontemporal_store(o, po + 32 * t + lo);
            }
        }
    }
}

extern "C" void kernel_launch(void* const* d_in, const int* in_sizes, int n_in,
                              void* d_out, int out_size, void* d_ws, size_t ws_size,
                              hipStream_t stream)
{
    const float* efeat    = (const float*)d_in[0];
    const float* src_feat = (const float*)d_in[1];
    const float* dst_feat = (const float*)d_in[2];
    const int*   src_idx  = (const int*)d_in[3];
    const int*   dst_idx  = (const int*)d_in[4];
    const float* w_efeat  = (const float*)d_in[5];
    const float* w_src    = (const float*)d_in[6];
    const float* w_dst    = (const float*)d_in[7];
    const float* b0       = (const float*)d_in[8];
    const float* w_out    = (const float*)d_in[9];
    const float* b_out    = (const float*)d_in[10];
    const float* ln_g     = (const float*)d_in[11];
    const float* ln_b     = (const float*)d_in[12];
    float* out = (float*)d_out;
    const int E = in_sizes[3];

    short* w1frag = (short*)d_ws;                          // 24*128*16 bf16 = 96 KB
    short* w2frag = (short*)((char*)d_ws + 24 * 128 * 16 * 2); // 8*128*16 bf16 = 32 KB

    prep_weights<<<256, 256, 0, stream>>>(w_efeat, w_src, w_dst, w_out, w1frag, w2frag);

    const int nb = (E + 127) / 128;
    edge_kernel<<<nb, 256, 0, stream>>>(efeat, src_feat, dst_feat, src_idx, dst_idx,
                                        b0, b_out, ln_g, ln_b, w1frag, w2frag, out, E);
}